// Round 2
// baseline (329.063 us; speedup 1.0000x reference)
//
#include <hip/hip_runtime.h>
#include <math.h>

namespace {
constexpr int B_ = 32, S_ = 1024, D_ = 256, N_ = 32, C_ = 64;
constexpr int NC_ = N_ * C_;  // 2048
constexpr int XP_ = 16;       // s-chunks per b (64 rows each)
constexpr unsigned NBLK = B_ * XP_;  // 512 blocks, 2/CU guaranteed resident

typedef __bf16 bf16x8 __attribute__((ext_vector_type(8)));
typedef __bf16 bf16x4 __attribute__((ext_vector_type(4)));
typedef float floatx4 __attribute__((ext_vector_type(4)));

constexpr int XS_ = 264;  // x_lds row stride (bf16)
constexpr int CS_ = 72;   // c_T row stride
}  // namespace

// Manual grid barrier: monotone epoch counter + go flag (both zeroed by a
// captured hipMemsetAsync before launch). Device-scope atomics + agent fences
// give cross-XCD visibility for the plain stores around it.
__device__ __forceinline__ void gsync(unsigned* cnt, unsigned* go, unsigned e,
                                      int t) {
  __syncthreads();  // all waves drain their stores (vmcnt(0) before s_barrier)
  if (t == 0) {
    __threadfence();  // wbl2: flush this XCD's L2 to the coherent point
    unsigned a = __hip_atomic_fetch_add(cnt, 1u, __ATOMIC_ACQ_REL,
                                        __HIP_MEMORY_SCOPE_AGENT) + 1u;
    if (a == e * NBLK) {
      __hip_atomic_store(go, e, __ATOMIC_RELEASE, __HIP_MEMORY_SCOPE_AGENT);
    } else {
      while (__hip_atomic_load(go, __ATOMIC_ACQUIRE,
                               __HIP_MEMORY_SCOPE_AGENT) < e) {
        __builtin_amdgcn_s_sleep(32);
      }
    }
    __threadfence();  // inv: drop stale L1/L2 lines before plain re-reads
  }
  __syncthreads();
}

// One fused kernel for the whole routing chain (plain launch, no cooperative
// API). Block bid = b*16+ch. Owns: x chunk [64 s x 256 d] bf16 in LDS (all
// phases), and capsules n = 2ch, 2ch+1 for the "small" phases (t in regs).
extern "C" __global__ __launch_bounds__(256, 2) void k_fused(
    const float* __restrict__ x, const float* __restrict__ W,
    float* __restrict__ out, float* __restrict__ xsum_part,
    float* __restrict__ y1, float* __restrict__ y2,
    __bf16* __restrict__ t_bhi, __bf16* __restrict__ t_blo,
    unsigned* bar_cnt, unsigned* bar_go) {
  __shared__ __align__(16) __bf16 x_lds[64 * XS_];   // 33792 B, persistent
  __shared__ __align__(16) __bf16 c_Th[N_ * CS_];    // 4608 B
  __shared__ __align__(16) __bf16 c_Tl[N_ * CS_];    // 4608 B
  __shared__ __align__(16) float scr[1024];          // xsum reduce / zloc
  __shared__ float sq_red[4][64];
  __shared__ float v_lds[64];

  const int bid = blockIdx.x;
  const int b = bid >> 4, ch = bid & 15;
  const int t = threadIdx.x, w = t >> 6, lane = t & 63;
  const int quad = lane >> 4, l16 = lane & 15;

  // ---- P0: x chunk -> bf16 LDS (once, resident) + xsum partial --------------
  {
    const float* xb = x + ((size_t)b * S_ + ch * 64) * D_;
    float s0 = 0.f, s1 = 0.f, s2 = 0.f, s3 = 0.f;
#pragma unroll
    for (int i = 0; i < 16; ++i) {
      int pos = i * 1024 + t * 4;
      int row = pos >> 8, col = pos & 255;
      float4 f = *(const float4*)(xb + pos);
      bf16x4 p4;
      p4[0] = (__bf16)f.x; p4[1] = (__bf16)f.y;
      p4[2] = (__bf16)f.z; p4[3] = (__bf16)f.w;
      *(bf16x4*)(x_lds + row * XS_ + col) = p4;
      s0 += f.x; s1 += f.y; s2 += f.z; s3 += f.w;
    }
    ((float4*)scr)[t] = make_float4(s0, s1, s2, s3);
  }
  __syncthreads();
  if (t < 64) {
    float4 a0 = ((float4*)scr)[t], a1 = ((float4*)scr)[t + 64],
           a2 = ((float4*)scr)[t + 128], a3 = ((float4*)scr)[t + 192];
    float4 r;
    r.x = a0.x + a1.x + a2.x + a3.x;
    r.y = a0.y + a1.y + a2.y + a3.y;
    r.z = a0.z + a1.z + a2.z + a3.z;
    r.w = a0.w + a1.w + a2.w + a3.w;
    *(float4*)(xsum_part + (size_t)bid * D_ + t * 4) = r;
  }

  // small phase: zloc from global, s = scale * zloc@W[n], v = squash -> v_lds
  auto small_sv = [&](const float* zsrc, int P, int zp, const float* Wn,
                      float scale) {
    __syncthreads();  // protect scr/v_lds reuse from previous phase
    float a = 0.f;
    for (int p = 0; p < P; ++p) a += zsrc[(size_t)p * zp + t];
    scr[t] = a;
    __syncthreads();
    const int c = t & 63, dq = t >> 6;
    float s = 0.f;
#pragma unroll 8
    for (int dd = 0; dd < 64; ++dd) {
      int d = dq * 64 + dd;
      s += scr[d] * Wn[d * 64 + c];
    }
    sq_red[dq][c] = s;
    __syncthreads();
    if (t < 64) {
      float sc =
          (sq_red[0][t] + sq_red[1][t] + sq_red[2][t] + sq_red[3][t]) * scale;
      float sq = sc * sc;
#pragma unroll
      for (int m = 1; m <= 32; m <<= 1) sq += __shfl_xor(sq, m);
      float scl = sq / ((1.f + sq) * sqrtf(sq + 1e-8f));
      v_lds[t] = sc * scl;
    }
    __syncthreads();
  };

  // t[d=t] = W[n][d,:] @ v
  auto wdotv = [&](const float* Wn) {
    const float4* W4 = (const float4*)Wn + t * 16;
    float acc = 0.f;
#pragma unroll
    for (int q = 0; q < 16; ++q) {
      float4 wv = W4[q];
      acc += wv.x * v_lds[q * 4] + wv.y * v_lds[q * 4 + 1] +
             wv.z * v_lds[q * 4 + 2] + wv.w * v_lds[q * 4 + 3];
    }
    return acc;
  };

  // routing pass: agr = x@t^T (MFMA, t hi/lo from global) -> softmax(n) ->
  // c_T (hi/lo, LDS) -> y[n,d] += c^T @ x (MFMA, fp32 atomics)
  auto pass = [&](float* y) {
    const __bf16* tbh = t_bhi + (size_t)b * (N_ * D_);
    const __bf16* tbl = t_blo + (size_t)b * (N_ * D_);
    floatx4 acc[2];
    acc[0] = (floatx4){0.f, 0.f, 0.f, 0.f};
    acc[1] = (floatx4){0.f, 0.f, 0.f, 0.f};
    const int sbase = w * 16;
#pragma unroll
    for (int k0 = 0; k0 < 256; k0 += 32) {
      int ks = k0 + quad * 8;
      bf16x8 bfrag = *(const bf16x8*)(x_lds + (sbase + l16) * XS_ + ks);
#pragma unroll
      for (int i = 0; i < 2; ++i) {
        bf16x8 ah = *(const bf16x8*)(tbh + (i * 16 + l16) * D_ + ks);
        bf16x8 al = *(const bf16x8*)(tbl + (i * 16 + l16) * D_ + ks);
        acc[i] = __builtin_amdgcn_mfma_f32_16x16x32_bf16(ah, bfrag, acc[i], 0, 0, 0);
        acc[i] = __builtin_amdgcn_mfma_f32_16x16x32_bf16(al, bfrag, acc[i], 0, 0, 0);
      }
    }
    // softmax over n for s = sbase + l16
    float mx = -1e30f;
#pragma unroll
    for (int i = 0; i < 2; ++i)
#pragma unroll
      for (int r = 0; r < 4; ++r) mx = fmaxf(mx, acc[i][r]);
    mx = fmaxf(mx, __shfl_xor(mx, 16));
    mx = fmaxf(mx, __shfl_xor(mx, 32));
    float e_[2][4];
    float ss = 0.f;
#pragma unroll
    for (int i = 0; i < 2; ++i)
#pragma unroll
      for (int r = 0; r < 4; ++r) {
        e_[i][r] = __expf(acc[i][r] - mx);
        ss += e_[i][r];
      }
    ss += __shfl_xor(ss, 16);
    ss += __shfl_xor(ss, 32);
    float inv = 1.f / ss;
#pragma unroll
    for (int i = 0; i < 2; ++i)
#pragma unroll
      for (int r = 0; r < 4; ++r) {
        float cv = e_[i][r] * inv;
        __bf16 chi = (__bf16)cv;
        int o = (i * 16 + quad * 4 + r) * CS_ + sbase + l16;
        c_Th[o] = chi;
        c_Tl[o] = (__bf16)(cv - (float)chi);
      }
    __syncthreads();

    floatx4 acc2[2][4];
#pragma unroll
    for (int i = 0; i < 2; ++i)
#pragma unroll
      for (int dt = 0; dt < 4; ++dt) acc2[i][dt] = (floatx4){0.f, 0.f, 0.f, 0.f};
    const int dbase = w * 64;
#pragma unroll
    for (int k0 = 0; k0 < 64; k0 += 32) {
      int ks = k0 + quad * 8;
      bf16x8 ah[2], al[2];
#pragma unroll
      for (int i = 0; i < 2; ++i) {
        ah[i] = *(const bf16x8*)(c_Th + (i * 16 + l16) * CS_ + ks);
        al[i] = *(const bf16x8*)(c_Tl + (i * 16 + l16) * CS_ + ks);
      }
#pragma unroll
      for (int dt = 0; dt < 4; ++dt) {
        bf16x8 bfr;
#pragma unroll
        for (int j8 = 0; j8 < 8; ++j8)
          bfr[j8] = x_lds[(ks + j8) * XS_ + dbase + dt * 16 + l16];
#pragma unroll
        for (int i = 0; i < 2; ++i) {
          acc2[i][dt] =
              __builtin_amdgcn_mfma_f32_16x16x32_bf16(ah[i], bfr, acc2[i][dt], 0, 0, 0);
          acc2[i][dt] =
              __builtin_amdgcn_mfma_f32_16x16x32_bf16(al[i], bfr, acc2[i][dt], 0, 0, 0);
        }
      }
    }
#pragma unroll
    for (int i = 0; i < 2; ++i)
#pragma unroll
      for (int dt = 0; dt < 4; ++dt)
#pragma unroll
        for (int r = 0; r < 4; ++r) {
          int n = i * 16 + quad * 4 + r;
          int d = dbase + dt * 16 + l16;
          atomicAdd(&y[((size_t)b * N_ + n) * D_ + d], acc2[i][dt][r]);
        }
    __syncthreads();
  };

  float treg[2];

  gsync(bar_cnt, bar_go, 1, t);

  // ---- iter 0: s = (1/N) xsum @ W -> v0 -> t0 = W@v0; zero y1 ---------------
#pragma unroll
  for (int j = 0; j < 2; ++j) {
    const int n = ch * 2 + j;
    const float* Wn = W + (size_t)n * (D_ * C_);
    small_sv(xsum_part + (size_t)b * XP_ * D_, XP_, D_, Wn, 1.f / 32.f);
    float acc = wdotv(Wn);
    treg[j] = acc;
    size_t idx = ((size_t)b * N_ + n) * D_ + t;
    __bf16 hi = (__bf16)acc;
    t_bhi[idx] = hi;
    t_blo[idx] = (__bf16)(acc - (float)hi);
    y1[idx] = 0.f;
  }

  gsync(bar_cnt, bar_go, 2, t);
  pass(y1);  // y1 = c1^T @ x
  gsync(bar_cnt, bar_go, 3, t);

  // ---- iter 1: s = y1 @ W -> v1; t01 = t0 + W@v1; zero y2 -------------------
#pragma unroll
  for (int j = 0; j < 2; ++j) {
    const int n = ch * 2 + j;
    const float* Wn = W + (size_t)n * (D_ * C_);
    small_sv(y1 + ((size_t)b * N_ + n) * D_, 1, 0, Wn, 1.f);
    float acc = treg[j] + wdotv(Wn);
    treg[j] = acc;
    size_t idx = ((size_t)b * N_ + n) * D_ + t;
    __bf16 hi = (__bf16)acc;
    t_bhi[idx] = hi;
    t_blo[idx] = (__bf16)(acc - (float)hi);
    y2[idx] = 0.f;
  }

  gsync(bar_cnt, bar_go, 4, t);
  pass(y2);  // y2 = c2^T @ x
  gsync(bar_cnt, bar_go, 5, t);

  // ---- iter 2: s = y2 @ W -> v2 -> out --------------------------------------
#pragma unroll
  for (int j = 0; j < 2; ++j) {
    const int n = ch * 2 + j;
    const float* Wn = W + (size_t)n * (D_ * C_);
    small_sv(y2 + ((size_t)b * N_ + n) * D_, 1, 0, Wn, 1.f);
    if (t < 64) out[(size_t)b * NC_ + n * 64 + t] = v_lds[t];
  }
}

extern "C" void kernel_launch(void* const* d_in, const int* in_sizes, int n_in,
                              void* d_out, int out_size, void* d_ws,
                              size_t ws_size, hipStream_t stream) {
  const float* x = (const float*)d_in[0];  // [B,S,D] fp32
  const float* W = (const float*)d_in[1];  // [N,D,C] fp32
  float* out = (float*)d_out;              // [B,N,C] fp32

  // ws (~3.5 MB + barrier): [xsum_part 512K | y1 1M | y2 1M | t_bhi 512K |
  //                          t_blo 512K | barrier 256B]
  char* ws = (char*)d_ws;
  float* xsum_part = (float*)ws;                 // [B,XP,D]
  float* y1 = (float*)(ws + 524288);             // [B,N,D]
  float* y2 = y1 + B_ * N_ * D_;                 // [B,N,D]
  __bf16* t_bhi = (__bf16*)(y2 + B_ * N_ * D_);  // [B,N,D]
  __bf16* t_blo = t_bhi + B_ * N_ * D_;          // [B,N,D]
  unsigned* bar = (unsigned*)(ws + 3670016);     // cnt @ [0], go @ [32]

  hipMemsetAsync(bar, 0, 256, stream);  // reset barrier (captured per replay)

  k_fused<<<dim3(NBLK), dim3(256), 0, stream>>>(x, W, out, xsum_part, y1, y2,
                                                t_bhi, t_blo, bar, bar + 32);
}

// Round 3
// 316.748 us; speedup vs baseline: 1.0389x; 1.0389x over previous
//
#include <hip/hip_runtime.h>
#include <math.h>

namespace {
constexpr int B_ = 32, S_ = 1024, D_ = 256, N_ = 32, C_ = 64;
constexpr int NC_ = N_ * C_;  // 2048
constexpr int XP_ = 16;       // s-chunks per b (64 rows each)
constexpr unsigned GRP = 16;  // blocks per barrier group (one batch b)

typedef __bf16 bf16x8 __attribute__((ext_vector_type(8)));
typedef __bf16 bf16x4 __attribute__((ext_vector_type(4)));
typedef float floatx4 __attribute__((ext_vector_type(4)));

constexpr int XS_ = 264;  // x_lds row stride (bf16)
constexpr int CS_ = 72;   // c_T row stride
}  // namespace

// Per-batch barrier: 16 blocks of batch b rendezvous on their own
// counter/flag pair (256 B apart per group -> no cross-group cacheline
// contention). Monotone epochs; both words zeroed by the launch-time memset.
__device__ __forceinline__ void gsync(unsigned* cnt, unsigned* go, unsigned e,
                                      int t) {
  __syncthreads();  // all waves drain their stores
  if (t == 0) {
    __threadfence();  // release: prior plain stores visible device-wide
    unsigned a = __hip_atomic_fetch_add(cnt, 1u, __ATOMIC_ACQ_REL,
                                        __HIP_MEMORY_SCOPE_AGENT) + 1u;
    if (a == e * GRP) {
      __hip_atomic_store(go, e, __ATOMIC_RELEASE, __HIP_MEMORY_SCOPE_AGENT);
    } else {
      while (__hip_atomic_load(go, __ATOMIC_ACQUIRE,
                               __HIP_MEMORY_SCOPE_AGENT) < e) {
        __builtin_amdgcn_s_sleep(4);
      }
    }
    __threadfence();  // acquire: drop stale lines before plain re-reads
  }
  __syncthreads();
}

// One fused kernel for the whole routing chain. Block bid = b*16+ch.
// Owns: x chunk [64 s x 256 d] bf16 in LDS (all phases), and capsules
// n = 2ch, 2ch+1 for the "small" phases (running t kept in registers).
extern "C" __global__ __launch_bounds__(256, 2) void k_fused(
    const float* __restrict__ x, const float* __restrict__ W,
    float* __restrict__ out, float* __restrict__ xsum_part,
    float* __restrict__ y1, float* __restrict__ y2,
    __bf16* __restrict__ t_bhi, __bf16* __restrict__ t_blo,
    unsigned* bar) {
  __shared__ __align__(16) __bf16 x_lds[64 * XS_];   // 33792 B, persistent
  __shared__ __align__(16) __bf16 c_Th[N_ * CS_];    // 4608 B
  __shared__ __align__(16) __bf16 c_Tl[N_ * CS_];    // 4608 B
  __shared__ __align__(16) float scr[1024];          // xsum reduce / zloc
  __shared__ float sq_red[4][64];
  __shared__ float v_lds[64];

  const int bid = blockIdx.x;
  const int b = bid >> 4, ch = bid & 15;
  const int t = threadIdx.x, w = t >> 6, lane = t & 63;
  const int quad = lane >> 4, l16 = lane & 15;

  unsigned* bcnt = bar + (size_t)b * 64;  // 256 B per group
  unsigned* bgo = bcnt + 32;

  // ---- P0: x chunk -> bf16 LDS (once, resident) + xsum partial --------------
  {
    const float* xb = x + ((size_t)b * S_ + ch * 64) * D_;
    float s0 = 0.f, s1 = 0.f, s2 = 0.f, s3 = 0.f;
#pragma unroll
    for (int i = 0; i < 16; ++i) {
      int pos = i * 1024 + t * 4;
      int row = pos >> 8, col = pos & 255;
      float4 f = *(const float4*)(xb + pos);
      bf16x4 p4;
      p4[0] = (__bf16)f.x; p4[1] = (__bf16)f.y;
      p4[2] = (__bf16)f.z; p4[3] = (__bf16)f.w;
      *(bf16x4*)(x_lds + row * XS_ + col) = p4;
      s0 += f.x; s1 += f.y; s2 += f.z; s3 += f.w;
    }
    ((float4*)scr)[t] = make_float4(s0, s1, s2, s3);
  }
  __syncthreads();
  if (t < 64) {
    float4 a0 = ((float4*)scr)[t], a1 = ((float4*)scr)[t + 64],
           a2 = ((float4*)scr)[t + 128], a3 = ((float4*)scr)[t + 192];
    float4 r;
    r.x = a0.x + a1.x + a2.x + a3.x;
    r.y = a0.y + a1.y + a2.y + a3.y;
    r.z = a0.z + a1.z + a2.z + a3.z;
    r.w = a0.w + a1.w + a2.w + a3.w;
    *(float4*)(xsum_part + (size_t)bid * D_ + t * 4) = r;
  }

  // small phase: zloc from global, s = scale * zloc@W[n], v = squash -> v_lds
  auto small_sv = [&](const float* zsrc, int P, int zp, const float* Wn,
                      float scale) {
    __syncthreads();  // protect scr/v_lds reuse from previous phase
    float a = 0.f;
    for (int p = 0; p < P; ++p) a += zsrc[(size_t)p * zp + t];
    scr[t] = a;
    __syncthreads();
    const int c = t & 63, dq = t >> 6;
    float s = 0.f;
#pragma unroll 8
    for (int dd = 0; dd < 64; ++dd) {
      int d = dq * 64 + dd;
      s += scr[d] * Wn[d * 64 + c];
    }
    sq_red[dq][c] = s;
    __syncthreads();
    if (t < 64) {
      float sc =
          (sq_red[0][t] + sq_red[1][t] + sq_red[2][t] + sq_red[3][t]) * scale;
      float sq = sc * sc;
#pragma unroll
      for (int m = 1; m <= 32; m <<= 1) sq += __shfl_xor(sq, m);
      float scl = sq / ((1.f + sq) * sqrtf(sq + 1e-8f));
      v_lds[t] = sc * scl;
    }
    __syncthreads();
  };

  // t[d=t] = W[n][d,:] @ v
  auto wdotv = [&](const float* Wn) {
    const float4* W4 = (const float4*)Wn + t * 16;
    float acc = 0.f;
#pragma unroll
    for (int q = 0; q < 16; ++q) {
      float4 wv = W4[q];
      acc += wv.x * v_lds[q * 4] + wv.y * v_lds[q * 4 + 1] +
             wv.z * v_lds[q * 4 + 2] + wv.w * v_lds[q * 4 + 3];
    }
    return acc;
  };

  // routing pass: agr = x@t^T (MFMA, t hi/lo from global) -> softmax(n) ->
  // c_T (hi/lo, LDS) -> y[n,d] += c^T @ x (MFMA, fp32 atomics)
  auto pass = [&](float* y) {
    const __bf16* tbh = t_bhi + (size_t)b * (N_ * D_);
    const __bf16* tbl = t_blo + (size_t)b * (N_ * D_);
    floatx4 acc[2];
    acc[0] = (floatx4){0.f, 0.f, 0.f, 0.f};
    acc[1] = (floatx4){0.f, 0.f, 0.f, 0.f};
    const int sbase = w * 16;
#pragma unroll
    for (int k0 = 0; k0 < 256; k0 += 32) {
      int ks = k0 + quad * 8;
      bf16x8 bfrag = *(const bf16x8*)(x_lds + (sbase + l16) * XS_ + ks);
#pragma unroll
      for (int i = 0; i < 2; ++i) {
        bf16x8 ah = *(const bf16x8*)(tbh + (i * 16 + l16) * D_ + ks);
        bf16x8 al = *(const bf16x8*)(tbl + (i * 16 + l16) * D_ + ks);
        acc[i] = __builtin_amdgcn_mfma_f32_16x16x32_bf16(ah, bfrag, acc[i], 0, 0, 0);
        acc[i] = __builtin_amdgcn_mfma_f32_16x16x32_bf16(al, bfrag, acc[i], 0, 0, 0);
      }
    }
    // softmax over n for s = sbase + l16
    float mx = -1e30f;
#pragma unroll
    for (int i = 0; i < 2; ++i)
#pragma unroll
      for (int r = 0; r < 4; ++r) mx = fmaxf(mx, acc[i][r]);
    mx = fmaxf(mx, __shfl_xor(mx, 16));
    mx = fmaxf(mx, __shfl_xor(mx, 32));
    float e_[2][4];
    float ss = 0.f;
#pragma unroll
    for (int i = 0; i < 2; ++i)
#pragma unroll
      for (int r = 0; r < 4; ++r) {
        e_[i][r] = __expf(acc[i][r] - mx);
        ss += e_[i][r];
      }
    ss += __shfl_xor(ss, 16);
    ss += __shfl_xor(ss, 32);
    float inv = 1.f / ss;
#pragma unroll
    for (int i = 0; i < 2; ++i)
#pragma unroll
      for (int r = 0; r < 4; ++r) {
        float cv = e_[i][r] * inv;
        __bf16 chi = (__bf16)cv;
        int o = (i * 16 + quad * 4 + r) * CS_ + sbase + l16;
        c_Th[o] = chi;
        c_Tl[o] = (__bf16)(cv - (float)chi);
      }
    __syncthreads();

    floatx4 acc2[2][4];
#pragma unroll
    for (int i = 0; i < 2; ++i)
#pragma unroll
      for (int dt = 0; dt < 4; ++dt) acc2[i][dt] = (floatx4){0.f, 0.f, 0.f, 0.f};
    const int dbase = w * 64;
#pragma unroll
    for (int k0 = 0; k0 < 64; k0 += 32) {
      int ks = k0 + quad * 8;
      bf16x8 ah[2], al[2];
#pragma unroll
      for (int i = 0; i < 2; ++i) {
        ah[i] = *(const bf16x8*)(c_Th + (i * 16 + l16) * CS_ + ks);
        al[i] = *(const bf16x8*)(c_Tl + (i * 16 + l16) * CS_ + ks);
      }
#pragma unroll
      for (int dt = 0; dt < 4; ++dt) {
        bf16x8 bfr;
#pragma unroll
        for (int j8 = 0; j8 < 8; ++j8)
          bfr[j8] = x_lds[(ks + j8) * XS_ + dbase + dt * 16 + l16];
#pragma unroll
        for (int i = 0; i < 2; ++i) {
          acc2[i][dt] =
              __builtin_amdgcn_mfma_f32_16x16x32_bf16(ah[i], bfr, acc2[i][dt], 0, 0, 0);
          acc2[i][dt] =
              __builtin_amdgcn_mfma_f32_16x16x32_bf16(al[i], bfr, acc2[i][dt], 0, 0, 0);
        }
      }
    }
#pragma unroll
    for (int i = 0; i < 2; ++i)
#pragma unroll
      for (int dt = 0; dt < 4; ++dt)
#pragma unroll
        for (int r = 0; r < 4; ++r) {
          int n = i * 16 + quad * 4 + r;
          int d = dbase + dt * 16 + l16;
          atomicAdd(&y[((size_t)b * N_ + n) * D_ + d], acc2[i][dt][r]);
        }
    __syncthreads();
  };

  float treg[2];

  gsync(bcnt, bgo, 1, t);

  // ---- iter 0: s = (1/N) xsum @ W -> v0 -> t0 = W@v0 ------------------------
#pragma unroll
  for (int j = 0; j < 2; ++j) {
    const int n = ch * 2 + j;
    const float* Wn = W + (size_t)n * (D_ * C_);
    small_sv(xsum_part + (size_t)b * XP_ * D_, XP_, D_, Wn, 1.f / 32.f);
    float acc = wdotv(Wn);
    treg[j] = acc;
    size_t idx = ((size_t)b * N_ + n) * D_ + t;
    __bf16 hi = (__bf16)acc;
    t_bhi[idx] = hi;
    t_blo[idx] = (__bf16)(acc - (float)hi);
  }

  gsync(bcnt, bgo, 2, t);
  pass(y1);  // y1 = c1^T @ x
  gsync(bcnt, bgo, 3, t);

  // ---- iter 1: s = y1 @ W -> v1; t01 = t0 + W@v1 ----------------------------
#pragma unroll
  for (int j = 0; j < 2; ++j) {
    const int n = ch * 2 + j;
    const float* Wn = W + (size_t)n * (D_ * C_);
    small_sv(y1 + ((size_t)b * N_ + n) * D_, 1, 0, Wn, 1.f);
    float acc = treg[j] + wdotv(Wn);
    treg[j] = acc;
    size_t idx = ((size_t)b * N_ + n) * D_ + t;
    __bf16 hi = (__bf16)acc;
    t_bhi[idx] = hi;
    t_blo[idx] = (__bf16)(acc - (float)hi);
  }

  gsync(bcnt, bgo, 4, t);
  pass(y2);  // y2 = c2^T @ x
  gsync(bcnt, bgo, 5, t);

  // ---- iter 2: s = y2 @ W -> v2 -> out --------------------------------------
#pragma unroll
  for (int j = 0; j < 2; ++j) {
    const int n = ch * 2 + j;
    const float* Wn = W + (size_t)n * (D_ * C_);
    small_sv(y2 + ((size_t)b * N_ + n) * D_, 1, 0, Wn, 1.f);
    if (t < 64) out[(size_t)b * NC_ + n * 64 + t] = v_lds[t];
  }
}

extern "C" void kernel_launch(void* const* d_in, const int* in_sizes, int n_in,
                              void* d_out, int out_size, void* d_ws,
                              size_t ws_size, hipStream_t stream) {
  const float* x = (const float*)d_in[0];  // [B,S,D] fp32
  const float* W = (const float*)d_in[1];  // [N,D,C] fp32
  float* out = (float*)d_out;              // [B,N,C] fp32

  // ws layout (zero-on-launch region contiguous at the end):
  //   [xsum_part 512K | t_bhi 512K | t_blo 512K | y1 1M | y2 1M | bar 8K]
  char* ws = (char*)d_ws;
  float* xsum_part = (float*)ws;                     // [B,XP,D] fp32
  __bf16* t_bhi = (__bf16*)(ws + 524288);            // [B,N,D] bf16
  __bf16* t_blo = t_bhi + B_ * N_ * D_;              // [B,N,D] bf16
  float* y1 = (float*)(ws + 1572864);                // [B,N,D] fp32
  float* y2 = y1 + B_ * N_ * D_;                     // [B,N,D] fp32
  unsigned* bar = (unsigned*)(ws + 3670016);         // 32 groups x 256 B

  // zero y1, y2 and the barrier words in one captured memset (2 MB + 8 KB)
  hipMemsetAsync(y1, 0, 2097152 + 8192, stream);

  k_fused<<<dim3(B_ * XP_), dim3(256), 0, stream>>>(x, W, out, xsum_part, y1,
                                                    y2, t_bhi, t_blo, bar);
}